// Round 2
// baseline (544.470 us; speedup 1.0000x reference)
//
#include <hip/hip_runtime.h>
#include <hip/hip_fp16.h>
#include <math.h>

#define N_NODES 100000
#define N_EDGES 3200000
#define F_INF   500
#define H_DIM   16
#define C_DIM   3

// bucket partition parameters
#define NB      782          // buckets of 128 nodes: bucket = dst >> 7
#define CAP     4608         // slots per bucket (mean 4096, sd ~64 -> +8 sigma)
#define GPAD    16           // gcur stride in ints (64B)
#define EPB     16384        // edges per partition block
#define NBLK_PART ((N_EDGES + EPB - 1) / EPB)   // 196

// workspace layout in 4-byte elements
#define OFF_GCUR  0                      // int[NB*GPAD] = 12512
#define OFF_DINV  12512                  // float[100000]
#define OFF_PAIRS 112512                 // uint[NB*CAP] = 3603456 (dst-sorted after k_sort)
#define OFF_ROWS  3715968                // int[NB*128] = 100096, packed (start_in_bucket<<16)|cnt
#define OFF_H1H   3816064                // uint[800000]: fp16 h1s rows (8 uints = 16 half)
#define OFF_H2H   4616064                // uint[200000]: fp16 h2s rows (2 uints = 4 half)

typedef float        f32x4 __attribute__((ext_vector_type(4)));
typedef unsigned int u32x4 __attribute__((ext_vector_type(4)));
typedef unsigned int u32x2 __attribute__((ext_vector_type(2)));

template <typename T>
__device__ inline T ntload(const T* p) { return __builtin_nontemporal_load(p); }
template <typename T>
__device__ inline void ntstore(T* p, T v) { __builtin_nontemporal_store(v, p); }

__device__ inline float2 h2f(unsigned u) {
    __half2 h = *reinterpret_cast<__half2*>(&u);
    return __half22float2(h);
}
__device__ inline unsigned f2h(float a, float b) {
    __half2 h = __floats2half2_rn(a, b);
    return *reinterpret_cast<unsigned*>(&h);
}

// ---------------- init per-bucket cursors ----------------
__global__ void k_init(int* __restrict__ gcur) {
    int b = blockIdx.x * 256 + threadIdx.x;
    if (b < NB) gcur[b * GPAD] = b * CAP;
}

// ---------------- bucket partition with in-LDS sort + coalesced flush ----------------
__global__ __launch_bounds__(512) void k_part(const int* __restrict__ src,
                                              const int* __restrict__ dst,
                                              int* __restrict__ gcur,
                                              unsigned int* __restrict__ pairs) {
    __shared__ unsigned sbuf[EPB];    // 64 KB staging, sorted by bucket
    __shared__ int lcnt[NB];
    __shared__ int lbase[NB];
    __shared__ int lstart[NB];
    __shared__ int lrank[NB];
    __shared__ int wtot[8];
    int t = threadIdx.x;
    int wid = t >> 6, lane = t & 63;
    int e0 = blockIdx.x * EPB;
    for (int i = t; i < NB; i += 512) { lcnt[i] = 0; lrank[i] = 0; }
    __syncthreads();
    // phase 1: histogram
    for (int i = t; i < EPB; i += 512) {
        int e = e0 + i;
        if (e < N_EDGES) atomicAdd(&lcnt[ntload(dst + e) >> 7], 1);
    }
    __syncthreads();
    // phase 2: global reserve
    for (int b = t; b < NB; b += 512) {
        int c = lcnt[b];
        lbase[b] = c ? atomicAdd(&gcur[b * GPAD], c) : 0;
    }
    // phase 2.5: block-local exclusive scan lcnt -> lstart (8 waves x 128 bins)
    {
        int b0 = wid * 128 + lane * 2;
        int c0 = (b0 < NB) ? lcnt[b0] : 0;
        int c1 = (b0 + 1 < NB) ? lcnt[b0 + 1] : 0;
        int s = c0 + c1;
        int inc = s;
        for (int o = 1; o < 64; o <<= 1) { int y = __shfl_up(inc, o); if (lane >= o) inc += y; }
        if (lane == 63) wtot[wid] = inc;
        int excl = inc - s;
        if (b0 < NB) lstart[b0] = excl;
        if (b0 + 1 < NB) lstart[b0 + 1] = excl + c0;
    }
    __syncthreads();
    if (t == 0) { int r = 0; for (int w = 0; w < 8; ++w) { int v = wtot[w]; wtot[w] = r; r += v; } }
    __syncthreads();
    {
        int b0 = wid * 128 + lane * 2;
        int add = wtot[wid];
        if (b0 < NB) lstart[b0] += add;
        if (b0 + 1 < NB) lstart[b0 + 1] += add;
    }
    __syncthreads();
    // phase 3: scatter into LDS staging (sorted by bucket)
    for (int i = t; i < EPB; i += 512) {
        int e = e0 + i;
        if (e < N_EDGES) {
            int d = ntload(dst + e);
            int b = d >> 7;
            int r = atomicAdd(&lrank[b], 1);
            sbuf[lstart[b] + r] = ((unsigned)ntload(src + e) << 7) | (unsigned)(d & 127);
        }
    }
    __syncthreads();
    // phase 4: coalesced flush, one wave per bucket round-robin
    for (int b = wid; b < NB; b += 8) {
        int c = lcnt[b], ls = lstart[b], gb = lbase[b];
        int lim = (b + 1) * CAP;
        for (int i = lane; i < c; i += 64) {
            int pos = gb + i;
            if (pos < lim)   // safety clamp (statistically never hit)
                pairs[pos] = sbuf[ls + i];
        }
    }
}

// ---------------- per-bucket counting sort by local dst -> CSR rows + dinv ----------------
__global__ __launch_bounds__(512) void k_sort(unsigned int* __restrict__ pairs,
                                              const int* __restrict__ gcur,
                                              float* __restrict__ dinv,
                                              int* __restrict__ rows) {
    __shared__ unsigned sbuf[CAP];   // 18 KB in
    __shared__ unsigned sout[CAP];   // 18 KB sorted
    __shared__ int cnt[128];
    __shared__ int start[128];
    __shared__ int rank[128];
    int b = blockIdx.x, t = threadIdx.x;
    if (t < 128) { cnt[t] = 0; rank[t] = 0; }
    __syncthreads();
    int base = b * CAP;
    int n = min(gcur[b * GPAD] - base, CAP);
    for (int i = t; i < n; i += 512) {
        unsigned p = ntload(pairs + base + i);
        sbuf[i] = p;
        atomicAdd(&cnt[p & 127], 1);
    }
    __syncthreads();
    // wave 0: exclusive scan of 128 bins + packed row table
    if (t < 64) {
        int c0 = cnt[2 * t], c1 = cnt[2 * t + 1];
        int s = c0 + c1;
        int inc = s;
        for (int o = 1; o < 64; o <<= 1) { int y = __shfl_up(inc, o); if (t >= o) inc += y; }
        int excl = inc - s;
        start[2 * t] = excl;
        start[2 * t + 1] = excl + c0;
        rows[b * 128 + 2 * t]     = (excl << 16) | c0;
        rows[b * 128 + 2 * t + 1] = ((excl + c0) << 16) | c1;
    }
    // waves 1-2: dinv from histogram (cnt is final after the barrier above)
    if (t >= 64 && t < 192) {
        int l = t - 64;
        int v = b * 128 + l;
        if (v < N_NODES) dinv[v] = rsqrtf((float)(cnt[l] + 1));
    }
    __syncthreads();
    // scatter to sorted LDS, then coalesced flush back to global
    for (int i = t; i < n; i += 512) {
        unsigned p = sbuf[i];
        int k = p & 127;
        int r = atomicAdd(&rank[k], 1);
        sout[start[k] + r] = p;
    }
    __syncthreads();
    for (int i = t; i < n; i += 512) ntstore(pairs + base + i, sout[i]);
}

// ---------------- GEMM1: h1h = fp16(dinv * (X @ W1)) ----------------
#define KTILE 60
#define KSTRIDE 61
__global__ __launch_bounds__(256) void k_gemm1(const float* __restrict__ x,
                                               const float* __restrict__ W1,
                                               const float* __restrict__ dinv,
                                               unsigned int* __restrict__ h1h) {
    __shared__ float xs[256 * KSTRIDE];  // 62.4 KB
    int t = threadIdx.x;
    int row0 = blockIdx.x * 256;
    int row = row0 + t;
    float acc[16];
#pragma unroll
    for (int j = 0; j < 16; ++j) acc[j] = 0.f;
    int rr = t >> 4;
    int cc = t & 15;
    for (int k0 = 0; k0 < F_INF; k0 += KTILE) {
        int kw = F_INF - k0; if (kw > KTILE) kw = KTILE;
        int nf4 = kw >> 2;
        __syncthreads();
#pragma unroll
        for (int s = 0; s < 16; ++s) {
            int r = s * 16 + rr;
            int gr = row0 + r;
            if (cc < nf4 && gr < N_NODES) {
                f32x4 v = ntload(reinterpret_cast<const f32x4*>(x + (size_t)gr * F_INF + k0 + cc * 4));
                float* q = xs + r * KSTRIDE + cc * 4;
                q[0] = v.x; q[1] = v.y; q[2] = v.z; q[3] = v.w;
            }
        }
        __syncthreads();
        if (row < N_NODES) {
            for (int kk = 0; kk < kw; ++kk) {
                float xv = xs[t * KSTRIDE + kk];
                const float* Wk = W1 + (k0 + kk) * 16;  // wave-uniform -> scalar loads
#pragma unroll
                for (int j = 0; j < 16; ++j) acc[j] = fmaf(xv, Wk[j], acc[j]);
            }
        }
    }
    if (row < N_NODES) {
        float dv = dinv[row];
        u32x4 o0, o1;
        o0.x = f2h(dv * acc[0],  dv * acc[1]);  o0.y = f2h(dv * acc[2],  dv * acc[3]);
        o0.z = f2h(dv * acc[4],  dv * acc[5]);  o0.w = f2h(dv * acc[6],  dv * acc[7]);
        o1.x = f2h(dv * acc[8],  dv * acc[9]);  o1.y = f2h(dv * acc[10], dv * acc[11]);
        o1.z = f2h(dv * acc[12], dv * acc[13]); o1.w = f2h(dv * acc[14], dv * acc[15]);
        u32x4* o = reinterpret_cast<u32x4*>(h1h + (size_t)row * 8);
        ntstore(o, o0);
        ntstore(o + 1, o1);
    }
}

// ---------------- AGG1 + fused GEMM2: CSR pull, 4 lanes per dst ----------------
// Each 4-lane group owns one dst row: lane q gathers+sums quarter q (4 floats)
// of the 16-feature h1 rows, applies dinv/bias/relu, then the group computes
// the 16x3 GEMM against W2 via in-register partials + 2 shfl_xor reduces.
__global__ __launch_bounds__(512) void k_agg1(const unsigned int* __restrict__ pairs,
                                              const int* __restrict__ rows,
                                              const float* __restrict__ dinv,
                                              const unsigned int* __restrict__ h1h,
                                              const float* __restrict__ b1,
                                              const float* __restrict__ W2,
                                              unsigned int* __restrict__ h2h) {
    int b = blockIdx.x, t = threadIdx.x;
    int q = t & 3;            // quarter of the 16-feature row (4 floats)
    int l = t >> 2;           // local dst 0..127
    int v = b * 128 + l;
    if (v >= N_NODES) return;
    int e = rows[b * 128 + l];
    int st = b * CAP + (e >> 16);
    int cnt = e & 0xffff;
    int qo = q * 2;           // uint offset into the 8-uint h1 row
    float dv = dinv[v];
    float s0 = 0.f, s1 = 0.f, s2 = 0.f, s3 = 0.f;
    int i = 0;
    for (; i + 8 <= cnt; i += 8) {
        unsigned p[8];
#pragma unroll
        for (int u = 0; u < 8; ++u) p[u] = ntload(pairs + st + i + u);
        u32x2 A[8];
#pragma unroll
        for (int u = 0; u < 8; ++u)
            A[u] = *reinterpret_cast<const u32x2*>(h1h + (size_t)(p[u] >> 7) * 8 + qo);
#pragma unroll
        for (int u = 0; u < 8; ++u) {
            float2 f0 = h2f(A[u].x), f1 = h2f(A[u].y);
            s0 += f0.x; s1 += f0.y; s2 += f1.x; s3 += f1.y;
        }
    }
    for (; i < cnt; ++i) {
        unsigned p = ntload(pairs + st + i);
        u32x2 A = *reinterpret_cast<const u32x2*>(h1h + (size_t)(p >> 7) * 8 + qo);
        float2 f0 = h2f(A.x), f1 = h2f(A.y);
        s0 += f0.x; s1 += f0.y; s2 += f1.x; s3 += f1.y;
    }
    // self loop (h1h already dinv[v]-scaled) + bias + relu -> a1 quarter in regs
    u32x2 S = *reinterpret_cast<const u32x2*>(h1h + (size_t)v * 8 + qo);
    float2 t0 = h2f(S.x), t1 = h2f(S.y);
    f32x4 bb = reinterpret_cast<const f32x4*>(b1)[q];
    float a0 = fmaxf(fmaf(dv, s0 + t0.x, bb.x), 0.f);
    float a1 = fmaxf(fmaf(dv, s1 + t0.y, bb.y), 0.f);
    float a2 = fmaxf(fmaf(dv, s2 + t1.x, bb.z), 0.f);
    float a3 = fmaxf(fmaf(dv, s3 + t1.y, bb.w), 0.f);
    // fused GEMM2: partial (4 of 16 k-terms) of a1row @ W2 [16x3]
    const float* Wq = W2 + q * 4 * 3;
    float c0 = fmaf(a0, Wq[0], fmaf(a1, Wq[3], fmaf(a2, Wq[6],  a3 * Wq[9])));
    float c1 = fmaf(a0, Wq[1], fmaf(a1, Wq[4], fmaf(a2, Wq[7],  a3 * Wq[10])));
    float c2 = fmaf(a0, Wq[2], fmaf(a1, Wq[5], fmaf(a2, Wq[8],  a3 * Wq[11])));
    // reduce across the 4-lane group (lanes l*4 .. l*4+3 are wave-contiguous)
    c0 += __shfl_xor(c0, 1); c0 += __shfl_xor(c0, 2);
    c1 += __shfl_xor(c1, 1); c1 += __shfl_xor(c1, 2);
    c2 += __shfl_xor(c2, 1); c2 += __shfl_xor(c2, 2);
    if (q == 0) {
        u32x2 o;
        o.x = f2h(dv * c0, dv * c1);
        o.y = f2h(dv * c2, 0.f);
        ntstore(reinterpret_cast<u32x2*>(h2h) + v, o);
    }
}

// ---------------- AGG2: CSR pull, 2 lanes per dst + bias + log_softmax ----------------
__global__ __launch_bounds__(256) void k_agg2(const unsigned int* __restrict__ pairs,
                                              const int* __restrict__ rows,
                                              const float* __restrict__ dinv,
                                              const unsigned int* __restrict__ h2h,
                                              const float* __restrict__ b2,
                                              float* __restrict__ out) {
    int b = blockIdx.x, t = threadIdx.x;
    int half = t & 1;         // stride-2 split of the run
    int l = t >> 1;           // local dst 0..127
    int v = b * 128 + l;
    if (v >= N_NODES) return; // both lanes of a pair exit together
    int e = rows[b * 128 + l];
    int st = b * CAP + (e >> 16);
    int cnt = e & 0xffff;
    const u32x2* h2v = reinterpret_cast<const u32x2*>(h2h);
    float c0 = 0.f, c1 = 0.f, c2 = 0.f;
    int i = half;
    for (; i + 6 < cnt; i += 8) {
        unsigned p0 = ntload(pairs + st + i);
        unsigned p1 = ntload(pairs + st + i + 2);
        unsigned p2 = ntload(pairs + st + i + 4);
        unsigned p3 = ntload(pairs + st + i + 6);
        u32x2 A = h2v[p0 >> 7];
        u32x2 B = h2v[p1 >> 7];
        u32x2 C = h2v[p2 >> 7];
        u32x2 D = h2v[p3 >> 7];
        float2 f01, f2_;
        f01 = h2f(A.x); f2_ = h2f(A.y); c0 += f01.x; c1 += f01.y; c2 += f2_.x;
        f01 = h2f(B.x); f2_ = h2f(B.y); c0 += f01.x; c1 += f01.y; c2 += f2_.x;
        f01 = h2f(C.x); f2_ = h2f(C.y); c0 += f01.x; c1 += f01.y; c2 += f2_.x;
        f01 = h2f(D.x); f2_ = h2f(D.y); c0 += f01.x; c1 += f01.y; c2 += f2_.x;
    }
    for (; i < cnt; i += 2) {
        unsigned p = ntload(pairs + st + i);
        u32x2 A = h2v[p >> 7];
        float2 f01 = h2f(A.x), f2_ = h2f(A.y);
        c0 += f01.x; c1 += f01.y; c2 += f2_.x;
    }
    // combine the stride-2 partials
    c0 += __shfl_xor(c0, 1);
    c1 += __shfl_xor(c1, 1);
    c2 += __shfl_xor(c2, 1);
    if (half == 0) {
        float dv = dinv[v];
        u32x2 hv = h2v[v];                       // self loop (already dv*h2)
        float2 f01 = h2f(hv.x), f2_ = h2f(hv.y);
        float z0 = fmaf(dv, c0 + f01.x, b2[0]);
        float z1 = fmaf(dv, c1 + f01.y, b2[1]);
        float z2 = fmaf(dv, c2 + f2_.x, b2[2]);
        float mx = fmaxf(z0, fmaxf(z1, z2));
        float lse = logf(expf(z0 - mx) + expf(z1 - mx) + expf(z2 - mx));
        out[v * 3 + 0] = z0 - mx - lse;
        out[v * 3 + 1] = z1 - mx - lse;
        out[v * 3 + 2] = z2 - mx - lse;
    }
}

extern "C" void kernel_launch(void* const* d_in, const int* in_sizes, int n_in,
                              void* d_out, int out_size, void* d_ws, size_t ws_size,
                              hipStream_t stream) {
    (void)in_sizes; (void)n_in; (void)out_size; (void)ws_size;
    const float* x  = (const float*)d_in[0];
    const float* W1 = (const float*)d_in[1];
    const float* b1 = (const float*)d_in[2];
    const float* W2 = (const float*)d_in[3];
    const float* b2 = (const float*)d_in[4];
    const int*   ei = (const int*)d_in[5];
    const int* src = ei;
    const int* dst = ei + N_EDGES;
    float* out = (float*)d_out;

    int* ws = (int*)d_ws;
    int*          gcur  = ws + OFF_GCUR;
    float*        dinv  = (float*)(ws + OFF_DINV);
    unsigned int* pairs = (unsigned int*)(ws + OFF_PAIRS);
    int*          rows  = ws + OFF_ROWS;
    unsigned int* h1h   = (unsigned int*)(ws + OFF_H1H);
    unsigned int* h2h   = (unsigned int*)(ws + OFF_H2H);

    k_init <<<(NB + 255) / 256, 256, 0, stream>>>(gcur);
    k_part <<<NBLK_PART, 512, 0, stream>>>(src, dst, gcur, pairs);
    k_sort <<<NB, 512, 0, stream>>>(pairs, gcur, dinv, rows);
    k_gemm1<<<(N_NODES + 255) / 256, 256, 0, stream>>>(x, W1, dinv, h1h);
    k_agg1 <<<NB, 512, 0, stream>>>(pairs, rows, dinv, h1h, b1, W2, h2h);
    k_agg2 <<<NB, 256, 0, stream>>>(pairs, rows, dinv, h2h, b2, out);
}

// Round 3
// 531.170 us; speedup vs baseline: 1.0250x; 1.0250x over previous
//
#include <hip/hip_runtime.h>
#include <hip/hip_fp16.h>
#include <math.h>

#define N_NODES 100000
#define N_EDGES 3200000
#define F_INF   500
#define H_DIM   16
#define C_DIM   3

// bucket partition parameters
#define NB      782          // buckets of 128 nodes: bucket = dst >> 7
#define CAP     4608         // slots per bucket (mean 4096, sd ~64 -> +8 sigma)
#define GPAD    16           // gcur stride in ints (64B)
#define EPB     16384        // edges per partition block
#define NBLK_PART ((N_EDGES + EPB - 1) / EPB)   // 196

// workspace layout in 4-byte elements
#define OFF_GCUR  0                      // int[NB*GPAD] = 12512
#define OFF_DINV  12512                  // float[100000]
#define OFF_PAIRS 112512                 // uint[NB*CAP] = 3603456 (dst-sorted after k_sort)
#define OFF_ROWS  3715968                // int[NB*128] = 100096, packed (start_in_bucket<<16)|cnt
#define OFF_H1H   3816064                // uint[800000]: fp16 h1s rows (8 uints = 16 half)
#define OFF_H2H   4616064                // uint[200000]: fp16 h2s rows (2 uints = 4 half)

typedef float        f32x4 __attribute__((ext_vector_type(4)));
typedef unsigned int u32x4 __attribute__((ext_vector_type(4)));
typedef unsigned int u32x2 __attribute__((ext_vector_type(2)));

template <typename T>
__device__ inline T ntload(const T* p) { return __builtin_nontemporal_load(p); }
template <typename T>
__device__ inline void ntstore(T* p, T v) { __builtin_nontemporal_store(v, p); }

__device__ inline float2 h2f(unsigned u) {
    __half2 h = *reinterpret_cast<__half2*>(&u);
    return __half22float2(h);
}
__device__ inline unsigned f2h(float a, float b) {
    __half2 h = __floats2half2_rn(a, b);
    return *reinterpret_cast<unsigned*>(&h);
}

// ---------------- init per-bucket cursors ----------------
__global__ void k_init(int* __restrict__ gcur) {
    int b = blockIdx.x * 256 + threadIdx.x;
    if (b < NB) gcur[b * GPAD] = b * CAP;
}

// ---------------- bucket partition with in-LDS sort + coalesced flush ----------------
__global__ __launch_bounds__(512) void k_part(const int* __restrict__ src,
                                              const int* __restrict__ dst,
                                              int* __restrict__ gcur,
                                              unsigned int* __restrict__ pairs) {
    __shared__ unsigned sbuf[EPB];    // 64 KB staging, sorted by bucket
    __shared__ int lcnt[NB];
    __shared__ int lbase[NB];
    __shared__ int lstart[NB];
    __shared__ int lrank[NB];
    __shared__ int wtot[8];
    int t = threadIdx.x;
    int wid = t >> 6, lane = t & 63;
    int e0 = blockIdx.x * EPB;
    for (int i = t; i < NB; i += 512) { lcnt[i] = 0; lrank[i] = 0; }
    __syncthreads();
    // phase 1: histogram
    for (int i = t; i < EPB; i += 512) {
        int e = e0 + i;
        if (e < N_EDGES) atomicAdd(&lcnt[ntload(dst + e) >> 7], 1);
    }
    __syncthreads();
    // phase 2: global reserve
    for (int b = t; b < NB; b += 512) {
        int c = lcnt[b];
        lbase[b] = c ? atomicAdd(&gcur[b * GPAD], c) : 0;
    }
    // phase 2.5: block-local exclusive scan lcnt -> lstart (8 waves x 128 bins)
    {
        int b0 = wid * 128 + lane * 2;
        int c0 = (b0 < NB) ? lcnt[b0] : 0;
        int c1 = (b0 + 1 < NB) ? lcnt[b0 + 1] : 0;
        int s = c0 + c1;
        int inc = s;
        for (int o = 1; o < 64; o <<= 1) { int y = __shfl_up(inc, o); if (lane >= o) inc += y; }
        if (lane == 63) wtot[wid] = inc;
        int excl = inc - s;
        if (b0 < NB) lstart[b0] = excl;
        if (b0 + 1 < NB) lstart[b0 + 1] = excl + c0;
    }
    __syncthreads();
    if (t == 0) { int r = 0; for (int w = 0; w < 8; ++w) { int v = wtot[w]; wtot[w] = r; r += v; } }
    __syncthreads();
    {
        int b0 = wid * 128 + lane * 2;
        int add = wtot[wid];
        if (b0 < NB) lstart[b0] += add;
        if (b0 + 1 < NB) lstart[b0 + 1] += add;
    }
    __syncthreads();
    // phase 3: scatter into LDS staging (sorted by bucket)
    for (int i = t; i < EPB; i += 512) {
        int e = e0 + i;
        if (e < N_EDGES) {
            int d = ntload(dst + e);
            int b = d >> 7;
            int r = atomicAdd(&lrank[b], 1);
            sbuf[lstart[b] + r] = ((unsigned)ntload(src + e) << 7) | (unsigned)(d & 127);
        }
    }
    __syncthreads();
    // phase 4: coalesced flush, one wave per bucket round-robin
    for (int b = wid; b < NB; b += 8) {
        int c = lcnt[b], ls = lstart[b], gb = lbase[b];
        int lim = (b + 1) * CAP;
        for (int i = lane; i < c; i += 64) {
            int pos = gb + i;
            if (pos < lim)   // safety clamp (statistically never hit)
                pairs[pos] = sbuf[ls + i];
        }
    }
}

// ---------------- per-bucket counting sort by local dst -> CSR rows + dinv ----------------
__global__ __launch_bounds__(512) void k_sort(unsigned int* __restrict__ pairs,
                                              const int* __restrict__ gcur,
                                              float* __restrict__ dinv,
                                              int* __restrict__ rows) {
    __shared__ unsigned sbuf[CAP];   // 18 KB in
    __shared__ unsigned sout[CAP];   // 18 KB sorted
    __shared__ int cnt[128];
    __shared__ int start[128];
    __shared__ int rank[128];
    int b = blockIdx.x, t = threadIdx.x;
    if (t < 128) { cnt[t] = 0; rank[t] = 0; }
    __syncthreads();
    int base = b * CAP;
    int n = min(gcur[b * GPAD] - base, CAP);
    for (int i = t; i < n; i += 512) {
        unsigned p = ntload(pairs + base + i);
        sbuf[i] = p;
        atomicAdd(&cnt[p & 127], 1);
    }
    __syncthreads();
    // wave 0: exclusive scan of 128 bins + packed row table
    if (t < 64) {
        int c0 = cnt[2 * t], c1 = cnt[2 * t + 1];
        int s = c0 + c1;
        int inc = s;
        for (int o = 1; o < 64; o <<= 1) { int y = __shfl_up(inc, o); if (t >= o) inc += y; }
        int excl = inc - s;
        start[2 * t] = excl;
        start[2 * t + 1] = excl + c0;
        rows[b * 128 + 2 * t]     = (excl << 16) | c0;
        rows[b * 128 + 2 * t + 1] = ((excl + c0) << 16) | c1;
    }
    // waves 1-2: dinv from histogram (cnt is final after the barrier above)
    if (t >= 64 && t < 192) {
        int l = t - 64;
        int v = b * 128 + l;
        if (v < N_NODES) dinv[v] = rsqrtf((float)(cnt[l] + 1));
    }
    __syncthreads();
    // scatter to sorted LDS, then coalesced flush back to global
    for (int i = t; i < n; i += 512) {
        unsigned p = sbuf[i];
        int k = p & 127;
        int r = atomicAdd(&rank[k], 1);
        sout[start[k] + r] = p;
    }
    __syncthreads();
    for (int i = t; i < n; i += 512) ntstore(pairs + base + i, sout[i]);
}

// ---------------- GEMM1: h1h = fp16(dinv * (X @ W1)) ----------------
// 128 rows/block (31.2 KB LDS -> 5 blocks/CU = 10 waves/CU) + register-staged
// prefetch: tile t+1's global loads are issued before tile t's compute, so the
// ~900-cycle HBM latency hides under the 60x16 FMA phase.
#define KTILE 60
#define KSTRIDE 61
#define GROWS 128
#define NTILE 9              // 8 x 60 + 1 x 20 = 500
__global__ __launch_bounds__(128) void k_gemm1(const float* __restrict__ x,
                                               const float* __restrict__ W1,
                                               const float* __restrict__ dinv,
                                               unsigned int* __restrict__ h1h) {
    __shared__ float xs[GROWS * KSTRIDE];  // 31.2 KB
    int t = threadIdx.x;
    int row0 = blockIdx.x * GROWS;
    int row = row0 + t;
    int rr = t >> 4;          // 0..7
    int cc = t & 15;          // 16B chunk within the k-tile
    float acc[16];
#pragma unroll
    for (int j = 0; j < 16; ++j) acc[j] = 0.f;
    f32x4 vreg[16];
    // prologue: issue tile 0 loads (kw=60 -> 15 chunks)
#pragma unroll
    for (int s = 0; s < 16; ++s) {
        int gr = row0 + s * 8 + rr;
        if (cc < 15 && gr < N_NODES)
            vreg[s] = ntload(reinterpret_cast<const f32x4*>(x + (size_t)gr * F_INF + cc * 4));
    }
    int k0 = 0;
    for (int tile = 0; tile < NTILE; ++tile) {
        int kw  = (tile < 8) ? KTILE : 20;
        int nf4 = kw >> 2;
        __syncthreads();      // previous compute done reading xs
        // drain in-flight loads (compiler emits vmcnt before first ds_write) and stage
#pragma unroll
        for (int s = 0; s < 16; ++s) {
            int r = s * 8 + rr;
            if (cc < nf4 && row0 + r < N_NODES) {
                float* q = xs + r * KSTRIDE + cc * 4;
                q[0] = vreg[s].x; q[1] = vreg[s].y; q[2] = vreg[s].z; q[3] = vreg[s].w;
            }
        }
        __syncthreads();
        // issue next tile's loads before compute (latency hides under FMAs)
        if (tile < NTILE - 1) {
            int nk0  = k0 + KTILE;
            int nnf4 = (tile < 7) ? 15 : 5;
#pragma unroll
            for (int s = 0; s < 16; ++s) {
                int gr = row0 + s * 8 + rr;
                if (cc < nnf4 && gr < N_NODES)
                    vreg[s] = ntload(reinterpret_cast<const f32x4*>(x + (size_t)gr * F_INF + nk0 + cc * 4));
            }
        }
        if (row < N_NODES) {
            for (int kk = 0; kk < kw; ++kk) {
                float xv = xs[t * KSTRIDE + kk];
                const float* Wk = W1 + (k0 + kk) * 16;  // wave-uniform -> scalar loads
#pragma unroll
                for (int j = 0; j < 16; ++j) acc[j] = fmaf(xv, Wk[j], acc[j]);
            }
        }
        k0 += KTILE;
    }
    if (row < N_NODES) {
        float dv = dinv[row];
        u32x4 o0, o1;
        o0.x = f2h(dv * acc[0],  dv * acc[1]);  o0.y = f2h(dv * acc[2],  dv * acc[3]);
        o0.z = f2h(dv * acc[4],  dv * acc[5]);  o0.w = f2h(dv * acc[6],  dv * acc[7]);
        o1.x = f2h(dv * acc[8],  dv * acc[9]);  o1.y = f2h(dv * acc[10], dv * acc[11]);
        o1.z = f2h(dv * acc[12], dv * acc[13]); o1.w = f2h(dv * acc[14], dv * acc[15]);
        u32x4* o = reinterpret_cast<u32x4*>(h1h + (size_t)row * 8);
        ntstore(o, o0);
        ntstore(o + 1, o1);
    }
}

// ---------------- AGG1 + fused GEMM2: CSR pull, 4 lanes per dst ----------------
// Each 4-lane group owns one dst row: lane q gathers+sums quarter q (4 floats)
// of the 16-feature h1 rows, applies dinv/bias/relu, then the group computes
// the 16x3 GEMM against W2 via in-register partials + 2 shfl_xor reduces.
__global__ __launch_bounds__(512) void k_agg1(const unsigned int* __restrict__ pairs,
                                              const int* __restrict__ rows,
                                              const float* __restrict__ dinv,
                                              const unsigned int* __restrict__ h1h,
                                              const float* __restrict__ b1,
                                              const float* __restrict__ W2,
                                              unsigned int* __restrict__ h2h) {
    int b = blockIdx.x, t = threadIdx.x;
    int q = t & 3;            // quarter of the 16-feature row (4 floats)
    int l = t >> 2;           // local dst 0..127
    int v = b * 128 + l;
    if (v >= N_NODES) return;
    int e = rows[b * 128 + l];
    int st = b * CAP + (e >> 16);
    int cnt = e & 0xffff;
    int qo = q * 2;           // uint offset into the 8-uint h1 row
    float dv = dinv[v];
    float s0 = 0.f, s1 = 0.f, s2 = 0.f, s3 = 0.f;
    int i = 0;
    for (; i + 8 <= cnt; i += 8) {
        unsigned p[8];
#pragma unroll
        for (int u = 0; u < 8; ++u) p[u] = ntload(pairs + st + i + u);
        u32x2 A[8];
#pragma unroll
        for (int u = 0; u < 8; ++u)
            A[u] = *reinterpret_cast<const u32x2*>(h1h + (size_t)(p[u] >> 7) * 8 + qo);
#pragma unroll
        for (int u = 0; u < 8; ++u) {
            float2 f0 = h2f(A[u].x), f1 = h2f(A[u].y);
            s0 += f0.x; s1 += f0.y; s2 += f1.x; s3 += f1.y;
        }
    }
    for (; i < cnt; ++i) {
        unsigned p = ntload(pairs + st + i);
        u32x2 A = *reinterpret_cast<const u32x2*>(h1h + (size_t)(p >> 7) * 8 + qo);
        float2 f0 = h2f(A.x), f1 = h2f(A.y);
        s0 += f0.x; s1 += f0.y; s2 += f1.x; s3 += f1.y;
    }
    // self loop (h1h already dinv[v]-scaled) + bias + relu -> a1 quarter in regs
    u32x2 S = *reinterpret_cast<const u32x2*>(h1h + (size_t)v * 8 + qo);
    float2 t0 = h2f(S.x), t1 = h2f(S.y);
    f32x4 bb = reinterpret_cast<const f32x4*>(b1)[q];
    float a0 = fmaxf(fmaf(dv, s0 + t0.x, bb.x), 0.f);
    float a1 = fmaxf(fmaf(dv, s1 + t0.y, bb.y), 0.f);
    float a2 = fmaxf(fmaf(dv, s2 + t1.x, bb.z), 0.f);
    float a3 = fmaxf(fmaf(dv, s3 + t1.y, bb.w), 0.f);
    // fused GEMM2: partial (4 of 16 k-terms) of a1row @ W2 [16x3]
    const float* Wq = W2 + q * 4 * 3;
    float c0 = fmaf(a0, Wq[0], fmaf(a1, Wq[3], fmaf(a2, Wq[6],  a3 * Wq[9])));
    float c1 = fmaf(a0, Wq[1], fmaf(a1, Wq[4], fmaf(a2, Wq[7],  a3 * Wq[10])));
    float c2 = fmaf(a0, Wq[2], fmaf(a1, Wq[5], fmaf(a2, Wq[8],  a3 * Wq[11])));
    // reduce across the 4-lane group (lanes l*4 .. l*4+3 are wave-contiguous)
    c0 += __shfl_xor(c0, 1); c0 += __shfl_xor(c0, 2);
    c1 += __shfl_xor(c1, 1); c1 += __shfl_xor(c1, 2);
    c2 += __shfl_xor(c2, 1); c2 += __shfl_xor(c2, 2);
    if (q == 0) {
        u32x2 o;
        o.x = f2h(dv * c0, dv * c1);
        o.y = f2h(dv * c2, 0.f);
        ntstore(reinterpret_cast<u32x2*>(h2h) + v, o);
    }
}

// ---------------- AGG2: CSR pull, 2 lanes per dst + bias + log_softmax ----------------
__global__ __launch_bounds__(256) void k_agg2(const unsigned int* __restrict__ pairs,
                                              const int* __restrict__ rows,
                                              const float* __restrict__ dinv,
                                              const unsigned int* __restrict__ h2h,
                                              const float* __restrict__ b2,
                                              float* __restrict__ out) {
    int b = blockIdx.x, t = threadIdx.x;
    int half = t & 1;         // stride-2 split of the run
    int l = t >> 1;           // local dst 0..127
    int v = b * 128 + l;
    if (v >= N_NODES) return; // both lanes of a pair exit together
    int e = rows[b * 128 + l];
    int st = b * CAP + (e >> 16);
    int cnt = e & 0xffff;
    const u32x2* h2v = reinterpret_cast<const u32x2*>(h2h);
    float c0 = 0.f, c1 = 0.f, c2 = 0.f;
    int i = half;
    for (; i + 6 < cnt; i += 8) {
        unsigned p0 = ntload(pairs + st + i);
        unsigned p1 = ntload(pairs + st + i + 2);
        unsigned p2 = ntload(pairs + st + i + 4);
        unsigned p3 = ntload(pairs + st + i + 6);
        u32x2 A = h2v[p0 >> 7];
        u32x2 B = h2v[p1 >> 7];
        u32x2 C = h2v[p2 >> 7];
        u32x2 D = h2v[p3 >> 7];
        float2 f01, f2_;
        f01 = h2f(A.x); f2_ = h2f(A.y); c0 += f01.x; c1 += f01.y; c2 += f2_.x;
        f01 = h2f(B.x); f2_ = h2f(B.y); c0 += f01.x; c1 += f01.y; c2 += f2_.x;
        f01 = h2f(C.x); f2_ = h2f(C.y); c0 += f01.x; c1 += f01.y; c2 += f2_.x;
        f01 = h2f(D.x); f2_ = h2f(D.y); c0 += f01.x; c1 += f01.y; c2 += f2_.x;
    }
    for (; i < cnt; i += 2) {
        unsigned p = ntload(pairs + st + i);
        u32x2 A = h2v[p >> 7];
        float2 f01 = h2f(A.x), f2_ = h2f(A.y);
        c0 += f01.x; c1 += f01.y; c2 += f2_.x;
    }
    // combine the stride-2 partials
    c0 += __shfl_xor(c0, 1);
    c1 += __shfl_xor(c1, 1);
    c2 += __shfl_xor(c2, 1);
    if (half == 0) {
        float dv = dinv[v];
        u32x2 hv = h2v[v];                       // self loop (already dv*h2)
        float2 f01 = h2f(hv.x), f2_ = h2f(hv.y);
        float z0 = fmaf(dv, c0 + f01.x, b2[0]);
        float z1 = fmaf(dv, c1 + f01.y, b2[1]);
        float z2 = fmaf(dv, c2 + f2_.x, b2[2]);
        float mx = fmaxf(z0, fmaxf(z1, z2));
        float lse = logf(expf(z0 - mx) + expf(z1 - mx) + expf(z2 - mx));
        out[v * 3 + 0] = z0 - mx - lse;
        out[v * 3 + 1] = z1 - mx - lse;
        out[v * 3 + 2] = z2 - mx - lse;
    }
}

extern "C" void kernel_launch(void* const* d_in, const int* in_sizes, int n_in,
                              void* d_out, int out_size, void* d_ws, size_t ws_size,
                              hipStream_t stream) {
    (void)in_sizes; (void)n_in; (void)out_size; (void)ws_size;
    const float* x  = (const float*)d_in[0];
    const float* W1 = (const float*)d_in[1];
    const float* b1 = (const float*)d_in[2];
    const float* W2 = (const float*)d_in[3];
    const float* b2 = (const float*)d_in[4];
    const int*   ei = (const int*)d_in[5];
    const int* src = ei;
    const int* dst = ei + N_EDGES;
    float* out = (float*)d_out;

    int* ws = (int*)d_ws;
    int*          gcur  = ws + OFF_GCUR;
    float*        dinv  = (float*)(ws + OFF_DINV);
    unsigned int* pairs = (unsigned int*)(ws + OFF_PAIRS);
    int*          rows  = ws + OFF_ROWS;
    unsigned int* h1h   = (unsigned int*)(ws + OFF_H1H);
    unsigned int* h2h   = (unsigned int*)(ws + OFF_H2H);

    k_init <<<(NB + 255) / 256, 256, 0, stream>>>(gcur);
    k_part <<<NBLK_PART, 512, 0, stream>>>(src, dst, gcur, pairs);
    k_sort <<<NB, 512, 0, stream>>>(pairs, gcur, dinv, rows);
    k_gemm1<<<NB, GROWS, 0, stream>>>(x, W1, dinv, h1h);
    k_agg1 <<<NB, 512, 0, stream>>>(pairs, rows, dinv, h1h, b1, W2, h2h);
    k_agg2 <<<NB, 256, 0, stream>>>(pairs, rows, dinv, h2h, b2, out);
}

// Round 5
// 524.854 us; speedup vs baseline: 1.0374x; 1.0120x over previous
//
#include <hip/hip_runtime.h>
#include <hip/hip_fp16.h>
#include <math.h>

#define N_NODES 100000
#define N_EDGES 3200000
#define F_INF   500
#define H_DIM   16
#define C_DIM   3

// bucket partition parameters
#define NB      782          // buckets of 128 nodes: bucket = dst >> 7
#define CAP     4608         // slots per bucket (mean 4096, sd ~64 -> +8 sigma)
#define GPAD    16           // gcur stride in ints (64B)
#define EPB     16384        // edges per partition block
#define NBLK_PART ((N_EDGES + EPB - 1) / EPB)   // 196

// workspace layout in 4-byte elements
#define OFF_GCUR  0                      // int[NB*GPAD] = 12512
#define OFF_DINV  12512                  // float[100000]
#define OFF_PAIRS 112512                 // uint[NB*CAP] = 3603456 (dst-sorted after k_sort)
#define OFF_ROWS  3715968                // int[NB*128] = 100096, packed (start_in_bucket<<16)|cnt
#define OFF_H1H   3816064                // uint[800000]: fp16 h1s rows (8 uints = 16 half)
#define OFF_H2H   4616064                // uint[200000]: fp16 h2s rows (2 uints = 4 half)

typedef float        f32x4 __attribute__((ext_vector_type(4)));
typedef unsigned int u32x4 __attribute__((ext_vector_type(4)));
typedef unsigned int u32x2 __attribute__((ext_vector_type(2)));

template <typename T>
__device__ inline T ntload(const T* p) { return __builtin_nontemporal_load(p); }
template <typename T>
__device__ inline void ntstore(T* p, T v) { __builtin_nontemporal_store(v, p); }

__device__ inline float2 h2f(unsigned u) {
    __half2 h = *reinterpret_cast<__half2*>(&u);
    return __half22float2(h);
}
__device__ inline unsigned f2h(float a, float b) {
    __half2 h = __floats2half2_rn(a, b);
    return *reinterpret_cast<unsigned*>(&h);
}

// ---------------- init per-bucket cursors ----------------
__global__ void k_init(int* __restrict__ gcur) {
    int b = blockIdx.x * 256 + threadIdx.x;
    if (b < NB) gcur[b * GPAD] = b * CAP;
}

// ---------------- bucket partition with in-LDS sort + coalesced flush ----------------
__global__ __launch_bounds__(512) void k_part(const int* __restrict__ src,
                                              const int* __restrict__ dst,
                                              int* __restrict__ gcur,
                                              unsigned int* __restrict__ pairs) {
    __shared__ unsigned sbuf[EPB];    // 64 KB staging, sorted by bucket
    __shared__ int lcnt[NB];
    __shared__ int lbase[NB];
    __shared__ int lstart[NB];
    __shared__ int lrank[NB];
    __shared__ int wtot[8];
    int t = threadIdx.x;
    int wid = t >> 6, lane = t & 63;
    int e0 = blockIdx.x * EPB;
    for (int i = t; i < NB; i += 512) { lcnt[i] = 0; lrank[i] = 0; }
    __syncthreads();
    // phase 1: histogram
    for (int i = t; i < EPB; i += 512) {
        int e = e0 + i;
        if (e < N_EDGES) atomicAdd(&lcnt[ntload(dst + e) >> 7], 1);
    }
    __syncthreads();
    // phase 2: global reserve
    for (int b = t; b < NB; b += 512) {
        int c = lcnt[b];
        lbase[b] = c ? atomicAdd(&gcur[b * GPAD], c) : 0;
    }
    // phase 2.5: block-local exclusive scan lcnt -> lstart (8 waves x 128 bins)
    {
        int b0 = wid * 128 + lane * 2;
        int c0 = (b0 < NB) ? lcnt[b0] : 0;
        int c1 = (b0 + 1 < NB) ? lcnt[b0 + 1] : 0;
        int s = c0 + c1;
        int inc = s;
        for (int o = 1; o < 64; o <<= 1) { int y = __shfl_up(inc, o); if (lane >= o) inc += y; }
        if (lane == 63) wtot[wid] = inc;
        int excl = inc - s;
        if (b0 < NB) lstart[b0] = excl;
        if (b0 + 1 < NB) lstart[b0 + 1] = excl + c0;
    }
    __syncthreads();
    if (t == 0) { int r = 0; for (int w = 0; w < 8; ++w) { int v = wtot[w]; wtot[w] = r; r += v; } }
    __syncthreads();
    {
        int b0 = wid * 128 + lane * 2;
        int add = wtot[wid];
        if (b0 < NB) lstart[b0] += add;
        if (b0 + 1 < NB) lstart[b0 + 1] += add;
    }
    __syncthreads();
    // phase 3: scatter into LDS staging (sorted by bucket)
    for (int i = t; i < EPB; i += 512) {
        int e = e0 + i;
        if (e < N_EDGES) {
            int d = ntload(dst + e);
            int b = d >> 7;
            int r = atomicAdd(&lrank[b], 1);
            sbuf[lstart[b] + r] = ((unsigned)ntload(src + e) << 7) | (unsigned)(d & 127);
        }
    }
    __syncthreads();
    // phase 4: coalesced flush, one wave per bucket round-robin
    for (int b = wid; b < NB; b += 8) {
        int c = lcnt[b], ls = lstart[b], gb = lbase[b];
        int lim = (b + 1) * CAP;
        for (int i = lane; i < c; i += 64) {
            int pos = gb + i;
            if (pos < lim)   // safety clamp (statistically never hit)
                pairs[pos] = sbuf[ls + i];
        }
    }
}

// ---------------- per-bucket counting sort by local dst -> CSR rows + dinv ----------------
__global__ __launch_bounds__(512) void k_sort(unsigned int* __restrict__ pairs,
                                              const int* __restrict__ gcur,
                                              float* __restrict__ dinv,
                                              int* __restrict__ rows) {
    __shared__ unsigned sbuf[CAP];   // 18 KB in
    __shared__ unsigned sout[CAP];   // 18 KB sorted
    __shared__ int cnt[128];
    __shared__ int start[128];
    __shared__ int rank[128];
    int b = blockIdx.x, t = threadIdx.x;
    if (t < 128) { cnt[t] = 0; rank[t] = 0; }
    __syncthreads();
    int base = b * CAP;
    int n = min(gcur[b * GPAD] - base, CAP);
    for (int i = t; i < n; i += 512) {
        unsigned p = ntload(pairs + base + i);
        sbuf[i] = p;
        atomicAdd(&cnt[p & 127], 1);
    }
    __syncthreads();
    // wave 0: exclusive scan of 128 bins + packed row table
    if (t < 64) {
        int c0 = cnt[2 * t], c1 = cnt[2 * t + 1];
        int s = c0 + c1;
        int inc = s;
        for (int o = 1; o < 64; o <<= 1) { int y = __shfl_up(inc, o); if (t >= o) inc += y; }
        int excl = inc - s;
        start[2 * t] = excl;
        start[2 * t + 1] = excl + c0;
        rows[b * 128 + 2 * t]     = (excl << 16) | c0;
        rows[b * 128 + 2 * t + 1] = ((excl + c0) << 16) | c1;
    }
    // waves 1-2: dinv from histogram (cnt is final after the barrier above)
    if (t >= 64 && t < 192) {
        int l = t - 64;
        int v = b * 128 + l;
        if (v < N_NODES) dinv[v] = rsqrtf((float)(cnt[l] + 1));
    }
    __syncthreads();
    // scatter to sorted LDS, then coalesced flush back to global
    for (int i = t; i < n; i += 512) {
        unsigned p = sbuf[i];
        int k = p & 127;
        int r = atomicAdd(&rank[k], 1);
        sout[start[k] + r] = p;
    }
    __syncthreads();
    for (int i = t; i < n; i += 512) ntstore(pairs + base + i, sout[i]);
}

// ---------------- GEMM1: h1h = fp16(dinv * (X @ W1)) ----------------
// Latency-bound fix (r4): KTILE 60->16 shrinks LDS to 8.7 KB so residency hits
// the 32-wave/CU cap (16 blocks x 2 waves = 8 waves/SIMD, was 2.5), and the
// compile-time tile width lets kk fully unroll (16 ds_read + batched s_loads +
// 256 FMA in flight, was 1 dependent load chain per kk). Register prefetch of
// tile t+1 (T14) kept to hide HBM staging latency.
#define KTILE 16
#define KSTRIDE 17           // odd -> 2-way-max LDS banking (free)
#define GROWS 128
#define NFULL 31             // 31*16 = 496
#define KTAIL 4              // 500 - 496
#define NTILE 32
__global__ __launch_bounds__(128, 8) void k_gemm1(const float* __restrict__ x,
                                                  const float* __restrict__ W1,
                                                  const float* __restrict__ dinv,
                                                  unsigned int* __restrict__ h1h) {
    __shared__ float xs[GROWS * KSTRIDE];  // 8.7 KB
    int t = threadIdx.x;
    int row0 = blockIdx.x * GROWS;
    int row = row0 + t;
    int cc = t & 3;           // 16B chunk within the k-tile (0..3)
    int rr = t >> 2;          // 0..31
    float acc[16];
#pragma unroll
    for (int j = 0; j < 16; ++j) acc[j] = 0.f;
    f32x4 vreg[4];
    // prologue: issue tile 0 loads (4 chunks of 4 rows-groups each)
#pragma unroll
    for (int s = 0; s < 4; ++s) {
        int gr = row0 + s * 32 + rr;
        if (gr < N_NODES)
            vreg[s] = ntload(reinterpret_cast<const f32x4*>(x + (size_t)gr * F_INF + cc * 4));
    }
#pragma unroll 1
    for (int tile = 0; tile < NTILE; ++tile) {
        int k0 = tile * KTILE;
        int nchunks = (tile < NFULL) ? 4 : 1;   // tail tile stages only 4 floats
        __syncthreads();      // previous compute done reading xs
#pragma unroll
        for (int s = 0; s < 4; ++s) {
            int r = s * 32 + rr;
            if (cc < nchunks && row0 + r < N_NODES) {
                float* q = xs + r * KSTRIDE + cc * 4;
                q[0] = vreg[s].x; q[1] = vreg[s].y; q[2] = vreg[s].z; q[3] = vreg[s].w;
            }
        }
        __syncthreads();
        // issue next tile's loads before compute (latency hides under FMAs)
        if (tile < NTILE - 1) {
            int nk0 = k0 + KTILE;
            int nnc = (tile + 1 < NFULL) ? 4 : 1;
#pragma unroll
            for (int s = 0; s < 4; ++s) {
                int gr = row0 + s * 32 + rr;
                if (cc < nnc && gr < N_NODES)
                    vreg[s] = ntload(reinterpret_cast<const f32x4*>(x + (size_t)gr * F_INF + nk0 + cc * 4));
            }
        }
        if (row < N_NODES) {
            const float* xrow = xs + t * KSTRIDE;
            const float* Wt = W1 + k0 * 16;     // wave-uniform -> scalar loads
            if (tile < NFULL) {
#pragma unroll
                for (int kk = 0; kk < KTILE; ++kk) {
                    float xv = xrow[kk];
#pragma unroll
                    for (int j = 0; j < 16; ++j) acc[j] = fmaf(xv, Wt[kk * 16 + j], acc[j]);
                }
            } else {
#pragma unroll
                for (int kk = 0; kk < KTAIL; ++kk) {
                    float xv = xrow[kk];
#pragma unroll
                    for (int j = 0; j < 16; ++j) acc[j] = fmaf(xv, Wt[kk * 16 + j], acc[j]);
                }
            }
        }
    }
    if (row < N_NODES) {
        float dv = dinv[row];
        u32x4 o0, o1;
        o0.x = f2h(dv * acc[0],  dv * acc[1]);  o0.y = f2h(dv * acc[2],  dv * acc[3]);
        o0.z = f2h(dv * acc[4],  dv * acc[5]);  o0.w = f2h(dv * acc[6],  dv * acc[7]);
        o1.x = f2h(dv * acc[8],  dv * acc[9]);  o1.y = f2h(dv * acc[10], dv * acc[11]);
        o1.z = f2h(dv * acc[12], dv * acc[13]); o1.w = f2h(dv * acc[14], dv * acc[15]);
        u32x4* o = reinterpret_cast<u32x4*>(h1h + (size_t)row * 8);
        ntstore(o, o0);
        ntstore(o + 1, o1);
    }
}

// ---------------- AGG1 + fused GEMM2: CSR pull, 4 lanes per dst ----------------
// Each 4-lane group owns one dst row: lane q gathers+sums quarter q (4 floats)
// of the 16-feature h1 rows, applies dinv/bias/relu, then the group computes
// the 16x3 GEMM against W2 via in-register partials + 2 shfl_xor reduces.
__global__ __launch_bounds__(512) void k_agg1(const unsigned int* __restrict__ pairs,
                                              const int* __restrict__ rows,
                                              const float* __restrict__ dinv,
                                              const unsigned int* __restrict__ h1h,
                                              const float* __restrict__ b1,
                                              const float* __restrict__ W2,
                                              unsigned int* __restrict__ h2h) {
    int b = blockIdx.x, t = threadIdx.x;
    int q = t & 3;            // quarter of the 16-feature row (4 floats)
    int l = t >> 2;           // local dst 0..127
    int v = b * 128 + l;
    if (v >= N_NODES) return;
    int e = rows[b * 128 + l];
    int st = b * CAP + (e >> 16);
    int cnt = e & 0xffff;
    int qo = q * 2;           // uint offset into the 8-uint h1 row
    float dv = dinv[v];
    float s0 = 0.f, s1 = 0.f, s2 = 0.f, s3 = 0.f;
    int i = 0;
    for (; i + 8 <= cnt; i += 8) {
        unsigned p[8];
#pragma unroll
        for (int u = 0; u < 8; ++u) p[u] = ntload(pairs + st + i + u);
        u32x2 A[8];
#pragma unroll
        for (int u = 0; u < 8; ++u)
            A[u] = *reinterpret_cast<const u32x2*>(h1h + (size_t)(p[u] >> 7) * 8 + qo);
#pragma unroll
        for (int u = 0; u < 8; ++u) {
            float2 f0 = h2f(A[u].x), f1 = h2f(A[u].y);
            s0 += f0.x; s1 += f0.y; s2 += f1.x; s3 += f1.y;
        }
    }
    for (; i < cnt; ++i) {
        unsigned p = ntload(pairs + st + i);
        u32x2 A = *reinterpret_cast<const u32x2*>(h1h + (size_t)(p >> 7) * 8 + qo);
        float2 f0 = h2f(A.x), f1 = h2f(A.y);
        s0 += f0.x; s1 += f0.y; s2 += f1.x; s3 += f1.y;
    }
    // self loop (h1h already dinv[v]-scaled) + bias + relu -> a1 quarter in regs
    u32x2 S = *reinterpret_cast<const u32x2*>(h1h + (size_t)v * 8 + qo);
    float2 t0 = h2f(S.x), t1 = h2f(S.y);
    f32x4 bb = reinterpret_cast<const f32x4*>(b1)[q];
    float a0 = fmaxf(fmaf(dv, s0 + t0.x, bb.x), 0.f);
    float a1 = fmaxf(fmaf(dv, s1 + t0.y, bb.y), 0.f);
    float a2 = fmaxf(fmaf(dv, s2 + t1.x, bb.z), 0.f);
    float a3 = fmaxf(fmaf(dv, s3 + t1.y, bb.w), 0.f);
    // fused GEMM2: partial (4 of 16 k-terms) of a1row @ W2 [16x3]
    const float* Wq = W2 + q * 4 * 3;
    float c0 = fmaf(a0, Wq[0], fmaf(a1, Wq[3], fmaf(a2, Wq[6],  a3 * Wq[9])));
    float c1 = fmaf(a0, Wq[1], fmaf(a1, Wq[4], fmaf(a2, Wq[7],  a3 * Wq[10])));
    float c2 = fmaf(a0, Wq[2], fmaf(a1, Wq[5], fmaf(a2, Wq[8],  a3 * Wq[11])));
    // reduce across the 4-lane group (lanes l*4 .. l*4+3 are wave-contiguous)
    c0 += __shfl_xor(c0, 1); c0 += __shfl_xor(c0, 2);
    c1 += __shfl_xor(c1, 1); c1 += __shfl_xor(c1, 2);
    c2 += __shfl_xor(c2, 1); c2 += __shfl_xor(c2, 2);
    if (q == 0) {
        u32x2 o;
        o.x = f2h(dv * c0, dv * c1);
        o.y = f2h(dv * c2, 0.f);
        ntstore(reinterpret_cast<u32x2*>(h2h) + v, o);
    }
}

// ---------------- AGG2: CSR pull, 2 lanes per dst + bias + log_softmax ----------------
__global__ __launch_bounds__(256) void k_agg2(const unsigned int* __restrict__ pairs,
                                              const int* __restrict__ rows,
                                              const float* __restrict__ dinv,
                                              const unsigned int* __restrict__ h2h,
                                              const float* __restrict__ b2,
                                              float* __restrict__ out) {
    int b = blockIdx.x, t = threadIdx.x;
    int half = t & 1;         // stride-2 split of the run
    int l = t >> 1;           // local dst 0..127
    int v = b * 128 + l;
    if (v >= N_NODES) return; // both lanes of a pair exit together
    int e = rows[b * 128 + l];
    int st = b * CAP + (e >> 16);
    int cnt = e & 0xffff;
    const u32x2* h2v = reinterpret_cast<const u32x2*>(h2h);
    float c0 = 0.f, c1 = 0.f, c2 = 0.f;
    int i = half;
    for (; i + 6 < cnt; i += 8) {
        unsigned p0 = ntload(pairs + st + i);
        unsigned p1 = ntload(pairs + st + i + 2);
        unsigned p2 = ntload(pairs + st + i + 4);
        unsigned p3 = ntload(pairs + st + i + 6);
        u32x2 A = h2v[p0 >> 7];
        u32x2 B = h2v[p1 >> 7];
        u32x2 C = h2v[p2 >> 7];
        u32x2 D = h2v[p3 >> 7];
        float2 f01, f2_;
        f01 = h2f(A.x); f2_ = h2f(A.y); c0 += f01.x; c1 += f01.y; c2 += f2_.x;
        f01 = h2f(B.x); f2_ = h2f(B.y); c0 += f01.x; c1 += f01.y; c2 += f2_.x;
        f01 = h2f(C.x); f2_ = h2f(C.y); c0 += f01.x; c1 += f01.y; c2 += f2_.x;
        f01 = h2f(D.x); f2_ = h2f(D.y); c0 += f01.x; c1 += f01.y; c2 += f2_.x;
    }
    for (; i < cnt; i += 2) {
        unsigned p = ntload(pairs + st + i);
        u32x2 A = h2v[p >> 7];
        float2 f01 = h2f(A.x), f2_ = h2f(A.y);
        c0 += f01.x; c1 += f01.y; c2 += f2_.x;
    }
    // combine the stride-2 partials
    c0 += __shfl_xor(c0, 1);
    c1 += __shfl_xor(c1, 1);
    c2 += __shfl_xor(c2, 1);
    if (half == 0) {
        float dv = dinv[v];
        u32x2 hv = h2v[v];                       // self loop (already dv*h2)
        float2 f01 = h2f(hv.x), f2_ = h2f(hv.y);
        float z0 = fmaf(dv, c0 + f01.x, b2[0]);
        float z1 = fmaf(dv, c1 + f01.y, b2[1]);
        float z2 = fmaf(dv, c2 + f2_.x, b2[2]);
        float mx = fmaxf(z0, fmaxf(z1, z2));
        float lse = logf(expf(z0 - mx) + expf(z1 - mx) + expf(z2 - mx));
        out[v * 3 + 0] = z0 - mx - lse;
        out[v * 3 + 1] = z1 - mx - lse;
        out[v * 3 + 2] = z2 - mx - lse;
    }
}

extern "C" void kernel_launch(void* const* d_in, const int* in_sizes, int n_in,
                              void* d_out, int out_size, void* d_ws, size_t ws_size,
                              hipStream_t stream) {
    (void)in_sizes; (void)n_in; (void)out_size; (void)ws_size;
    const float* x  = (const float*)d_in[0];
    const float* W1 = (const float*)d_in[1];
    const float* b1 = (const float*)d_in[2];
    const float* W2 = (const float*)d_in[3];
    const float* b2 = (const float*)d_in[4];
    const int*   ei = (const int*)d_in[5];
    const int* src = ei;
    const int* dst = ei + N_EDGES;
    float* out = (float*)d_out;

    int* ws = (int*)d_ws;
    int*          gcur  = ws + OFF_GCUR;
    float*        dinv  = (float*)(ws + OFF_DINV);
    unsigned int* pairs = (unsigned int*)(ws + OFF_PAIRS);
    int*          rows  = ws + OFF_ROWS;
    unsigned int* h1h   = (unsigned int*)(ws + OFF_H1H);
    unsigned int* h2h   = (unsigned int*)(ws + OFF_H2H);

    k_init <<<(NB + 255) / 256, 256, 0, stream>>>(gcur);
    k_part <<<NBLK_PART, 512, 0, stream>>>(src, dst, gcur, pairs);
    k_sort <<<NB, 512, 0, stream>>>(pairs, gcur, dinv, rows);
    k_gemm1<<<NB, GROWS, 0, stream>>>(x, W1, dinv, h1h);
    k_agg1 <<<NB, 512, 0, stream>>>(pairs, rows, dinv, h1h, b1, W2, h2h);
    k_agg2 <<<NB, 256, 0, stream>>>(pairs, rows, dinv, h2h, b2, out);
}

// Round 6
// 489.508 us; speedup vs baseline: 1.1123x; 1.0722x over previous
//
#include <hip/hip_runtime.h>
#include <hip/hip_fp16.h>
#include <math.h>

#define N_NODES 100000
#define N_EDGES 3200000
#define F_INF   500
#define H_DIM   16
#define C_DIM   3

// bucket partition parameters
#define NB      782          // buckets of 128 nodes: bucket = dst >> 7
#define CAP     4608         // slots per bucket (mean 4096, sd ~64 -> +8 sigma)
#define GPAD    16           // gcur stride in ints (64B)
#define EPB     16384        // edges per partition block
#define NBLK_PART ((N_EDGES + EPB - 1) / EPB)   // 196

// workspace layout in 4-byte elements
#define OFF_GCUR  0                      // int[NB*GPAD] = 12512
#define OFF_DINV  12512                  // float[100000]
#define OFF_PAIRS 112512                 // uint[NB*CAP] = 3603456 (dst-sorted after k_sort)
#define OFF_ROWS  3715968                // int[NB*128] = 100096, packed (start_in_bucket<<16)|cnt
#define OFF_H1H   3816064                // uint[800000]: fp16 h1s rows (8 uints = 16 half)
#define OFF_H2H   4616064                // uint[200000]: fp16 h2s rows (2 uints = 4 half)

typedef float        f32x4 __attribute__((ext_vector_type(4)));
typedef unsigned int u32x4 __attribute__((ext_vector_type(4)));
typedef unsigned int u32x2 __attribute__((ext_vector_type(2)));

template <typename T>
__device__ inline T ntload(const T* p) { return __builtin_nontemporal_load(p); }
template <typename T>
__device__ inline void ntstore(T* p, T v) { __builtin_nontemporal_store(v, p); }

__device__ inline float2 h2f(unsigned u) {
    __half2 h = *reinterpret_cast<__half2*>(&u);
    return __half22float2(h);
}
__device__ inline unsigned f2h(float a, float b) {
    __half2 h = __floats2half2_rn(a, b);
    return *reinterpret_cast<unsigned*>(&h);
}

// ---------------- init per-bucket cursors ----------------
__global__ void k_init(int* __restrict__ gcur) {
    int b = blockIdx.x * 256 + threadIdx.x;
    if (b < NB) gcur[b * GPAD] = b * CAP;
}

// ---------------- bucket partition with in-LDS sort + coalesced flush ----------------
__global__ __launch_bounds__(512) void k_part(const int* __restrict__ src,
                                              const int* __restrict__ dst,
                                              int* __restrict__ gcur,
                                              unsigned int* __restrict__ pairs) {
    __shared__ unsigned sbuf[EPB];    // 64 KB staging, sorted by bucket
    __shared__ int lcnt[NB];
    __shared__ int lbase[NB];
    __shared__ int lstart[NB];
    __shared__ int lrank[NB];
    __shared__ int wtot[8];
    int t = threadIdx.x;
    int wid = t >> 6, lane = t & 63;
    int e0 = blockIdx.x * EPB;
    for (int i = t; i < NB; i += 512) { lcnt[i] = 0; lrank[i] = 0; }
    __syncthreads();
    // phase 1: histogram
    for (int i = t; i < EPB; i += 512) {
        int e = e0 + i;
        if (e < N_EDGES) atomicAdd(&lcnt[ntload(dst + e) >> 7], 1);
    }
    __syncthreads();
    // phase 2: global reserve
    for (int b = t; b < NB; b += 512) {
        int c = lcnt[b];
        lbase[b] = c ? atomicAdd(&gcur[b * GPAD], c) : 0;
    }
    // phase 2.5: block-local exclusive scan lcnt -> lstart (8 waves x 128 bins)
    {
        int b0 = wid * 128 + lane * 2;
        int c0 = (b0 < NB) ? lcnt[b0] : 0;
        int c1 = (b0 + 1 < NB) ? lcnt[b0 + 1] : 0;
        int s = c0 + c1;
        int inc = s;
        for (int o = 1; o < 64; o <<= 1) { int y = __shfl_up(inc, o); if (lane >= o) inc += y; }
        if (lane == 63) wtot[wid] = inc;
        int excl = inc - s;
        if (b0 < NB) lstart[b0] = excl;
        if (b0 + 1 < NB) lstart[b0 + 1] = excl + c0;
    }
    __syncthreads();
    if (t == 0) { int r = 0; for (int w = 0; w < 8; ++w) { int v = wtot[w]; wtot[w] = r; r += v; } }
    __syncthreads();
    {
        int b0 = wid * 128 + lane * 2;
        int add = wtot[wid];
        if (b0 < NB) lstart[b0] += add;
        if (b0 + 1 < NB) lstart[b0 + 1] += add;
    }
    __syncthreads();
    // phase 3: scatter into LDS staging (sorted by bucket)
    for (int i = t; i < EPB; i += 512) {
        int e = e0 + i;
        if (e < N_EDGES) {
            int d = ntload(dst + e);
            int b = d >> 7;
            int r = atomicAdd(&lrank[b], 1);
            sbuf[lstart[b] + r] = ((unsigned)ntload(src + e) << 7) | (unsigned)(d & 127);
        }
    }
    __syncthreads();
    // phase 4: coalesced flush, one wave per bucket round-robin
    for (int b = wid; b < NB; b += 8) {
        int c = lcnt[b], ls = lstart[b], gb = lbase[b];
        int lim = (b + 1) * CAP;
        for (int i = lane; i < c; i += 64) {
            int pos = gb + i;
            if (pos < lim)   // safety clamp (statistically never hit)
                pairs[pos] = sbuf[ls + i];
        }
    }
}

// ---------------- per-bucket counting sort by local dst -> CSR rows + dinv ----------------
__global__ __launch_bounds__(512) void k_sort(unsigned int* __restrict__ pairs,
                                              const int* __restrict__ gcur,
                                              float* __restrict__ dinv,
                                              int* __restrict__ rows) {
    __shared__ unsigned sbuf[CAP];   // 18 KB in
    __shared__ unsigned sout[CAP];   // 18 KB sorted
    __shared__ int cnt[128];
    __shared__ int start[128];
    __shared__ int rank[128];
    int b = blockIdx.x, t = threadIdx.x;
    if (t < 128) { cnt[t] = 0; rank[t] = 0; }
    __syncthreads();
    int base = b * CAP;
    int n = min(gcur[b * GPAD] - base, CAP);
    for (int i = t; i < n; i += 512) {
        unsigned p = ntload(pairs + base + i);
        sbuf[i] = p;
        atomicAdd(&cnt[p & 127], 1);
    }
    __syncthreads();
    // wave 0: exclusive scan of 128 bins + packed row table
    if (t < 64) {
        int c0 = cnt[2 * t], c1 = cnt[2 * t + 1];
        int s = c0 + c1;
        int inc = s;
        for (int o = 1; o < 64; o <<= 1) { int y = __shfl_up(inc, o); if (t >= o) inc += y; }
        int excl = inc - s;
        start[2 * t] = excl;
        start[2 * t + 1] = excl + c0;
        rows[b * 128 + 2 * t]     = (excl << 16) | c0;
        rows[b * 128 + 2 * t + 1] = ((excl + c0) << 16) | c1;
    }
    // waves 1-2: dinv from histogram (cnt is final after the barrier above)
    if (t >= 64 && t < 192) {
        int l = t - 64;
        int v = b * 128 + l;
        if (v < N_NODES) dinv[v] = rsqrtf((float)(cnt[l] + 1));
    }
    __syncthreads();
    // scatter to sorted LDS, then coalesced flush back to global
    for (int i = t; i < n; i += 512) {
        unsigned p = sbuf[i];
        int k = p & 127;
        int r = atomicAdd(&rank[k], 1);
        sout[start[k] + r] = p;
    }
    __syncthreads();
    for (int i = t; i < n; i += 512) ntstore(pairs + base + i, sout[i]);
}

// ---------------- GEMM1: h1h = fp16(dinv * (X @ W1)) ----------------
// r6: occupancy was grid-capped (782 blk x 2 waves = 6.1 waves/CU, measured
// 17.4%) and the W-tile s_load chain serialized the unrolled body (80 SGPRs
// can't hold 256 W floats -> chunked s_load->wait->FMA). Fix: 512 threads /
// 4 threads per row (4 cols each) -> 24 waves/CU (3 blk x 8 waves, LDS 42 KB);
// W1 staged ENTIRELY in LDS once (32 KB) -> inner loop is pure ds_read_b128
// (x broadcast + W 4-addr broadcast, conflict-free) + FMA. K-order per output
// unchanged -> bitwise-identical results.
#define KTILE 16
#define KSTRIDE 20           // 80 B rows: b128-aligned, 2-way bank alias (free)
#define GROWS 128
#define NFULL 31             // 31*16 = 496
#define NTILE 32             // tail tile = 4 k-values
__global__ __launch_bounds__(512, 6) void k_gemm1(const float* __restrict__ x,
                                                  const float* __restrict__ W1,
                                                  const float* __restrict__ dinv,
                                                  unsigned int* __restrict__ h1h) {
    __shared__ float xs[GROWS * KSTRIDE];   // 10.2 KB
    __shared__ float wlds[F_INF * 16];      // 32.0 KB
    int t = threadIdx.x;
    int row0 = blockIdx.x * GROWS;
    int q = t & 3;            // column quarter (cols q*4 .. q*4+3)
    int r = t >> 2;           // local row 0..127
    int row = row0 + r;
    bool rowok = row < N_NODES;

    // stage all of W1 into LDS (once per block; first loop barrier fences it)
    {
        const f32x4* Wg = reinterpret_cast<const f32x4*>(W1);
        f32x4* Wl = reinterpret_cast<f32x4*>(wlds);
        for (int i = t; i < F_INF * 4; i += 512) Wl[i] = ntload(Wg + i);
    }

    float acc[4] = {0.f, 0.f, 0.f, 0.f};
    // x staging: thread t owns (row r, 16B chunk q) of each k-tile.
    // 4-lane groups load 64 B contiguous per row -> coalesced 64B transactions.
    f32x4 vreg;
    if (rowok)
        vreg = ntload(reinterpret_cast<const f32x4*>(x + (size_t)row * F_INF + q * 4));

#pragma unroll 1
    for (int tile = 0; tile < NTILE; ++tile) {
        int k0 = tile * KTILE;
        __syncthreads();      // xs consumers done (also fences W staging, tile 0)
        if (rowok && (tile < NFULL || q == 0)) {
            float* p = xs + r * KSTRIDE + q * 4;
            p[0] = vreg.x; p[1] = vreg.y; p[2] = vreg.z; p[3] = vreg.w;
        }
        __syncthreads();
        // issue next tile's loads; HBM latency hides under compute (T14)
        if (tile < NTILE - 1) {
            int nk0 = k0 + KTILE;
            if (rowok && (tile + 1 < NFULL || q == 0))
                vreg = ntload(reinterpret_cast<const f32x4*>(x + (size_t)row * F_INF + nk0 + q * 4));
        }
        if (rowok) {
            const float* xrow = xs + r * KSTRIDE;
            const float* wq = wlds + k0 * 16 + q * 4;
            if (tile < NFULL) {
#pragma unroll
                for (int g = 0; g < 4; ++g) {
                    f32x4 xv = *reinterpret_cast<const f32x4*>(xrow + g * 4);
#pragma unroll
                    for (int kk = 0; kk < 4; ++kk) {
                        f32x4 wv = *reinterpret_cast<const f32x4*>(wq + (g * 4 + kk) * 16);
                        float xvk = xv[kk];
                        acc[0] = fmaf(xvk, wv.x, acc[0]);
                        acc[1] = fmaf(xvk, wv.y, acc[1]);
                        acc[2] = fmaf(xvk, wv.z, acc[2]);
                        acc[3] = fmaf(xvk, wv.w, acc[3]);
                    }
                }
            } else {
                f32x4 xv = *reinterpret_cast<const f32x4*>(xrow);
#pragma unroll
                for (int kk = 0; kk < 4; ++kk) {
                    f32x4 wv = *reinterpret_cast<const f32x4*>(wq + kk * 16);
                    float xvk = xv[kk];
                    acc[0] = fmaf(xvk, wv.x, acc[0]);
                    acc[1] = fmaf(xvk, wv.y, acc[1]);
                    acc[2] = fmaf(xvk, wv.z, acc[2]);
                    acc[3] = fmaf(xvk, wv.w, acc[3]);
                }
            }
        }
    }
    if (rowok) {
        float dv = dinv[row];
        u32x2 o;
        o.x = f2h(dv * acc[0], dv * acc[1]);
        o.y = f2h(dv * acc[2], dv * acc[3]);
        // 4 lanes per row cover the 32B h1 row contiguously -> coalesced
        ntstore(reinterpret_cast<u32x2*>(h1h + (size_t)row * 8 + q * 2), o);
    }
}

// ---------------- AGG1 + fused GEMM2: CSR pull, 4 lanes per dst ----------------
// Each 4-lane group owns one dst row: lane q gathers+sums quarter q (4 floats)
// of the 16-feature h1 rows, applies dinv/bias/relu, then the group computes
// the 16x3 GEMM against W2 via in-register partials + 2 shfl_xor reduces.
__global__ __launch_bounds__(512) void k_agg1(const unsigned int* __restrict__ pairs,
                                              const int* __restrict__ rows,
                                              const float* __restrict__ dinv,
                                              const unsigned int* __restrict__ h1h,
                                              const float* __restrict__ b1,
                                              const float* __restrict__ W2,
                                              unsigned int* __restrict__ h2h) {
    int b = blockIdx.x, t = threadIdx.x;
    int q = t & 3;            // quarter of the 16-feature row (4 floats)
    int l = t >> 2;           // local dst 0..127
    int v = b * 128 + l;
    if (v >= N_NODES) return;
    int e = rows[b * 128 + l];
    int st = b * CAP + (e >> 16);
    int cnt = e & 0xffff;
    int qo = q * 2;           // uint offset into the 8-uint h1 row
    float dv = dinv[v];
    float s0 = 0.f, s1 = 0.f, s2 = 0.f, s3 = 0.f;
    int i = 0;
    for (; i + 8 <= cnt; i += 8) {
        unsigned p[8];
#pragma unroll
        for (int u = 0; u < 8; ++u) p[u] = ntload(pairs + st + i + u);
        u32x2 A[8];
#pragma unroll
        for (int u = 0; u < 8; ++u)
            A[u] = *reinterpret_cast<const u32x2*>(h1h + (size_t)(p[u] >> 7) * 8 + qo);
#pragma unroll
        for (int u = 0; u < 8; ++u) {
            float2 f0 = h2f(A[u].x), f1 = h2f(A[u].y);
            s0 += f0.x; s1 += f0.y; s2 += f1.x; s3 += f1.y;
        }
    }
    for (; i < cnt; ++i) {
        unsigned p = ntload(pairs + st + i);
        u32x2 A = *reinterpret_cast<const u32x2*>(h1h + (size_t)(p >> 7) * 8 + qo);
        float2 f0 = h2f(A.x), f1 = h2f(A.y);
        s0 += f0.x; s1 += f0.y; s2 += f1.x; s3 += f1.y;
    }
    // self loop (h1h already dinv[v]-scaled) + bias + relu -> a1 quarter in regs
    u32x2 S = *reinterpret_cast<const u32x2*>(h1h + (size_t)v * 8 + qo);
    float2 t0 = h2f(S.x), t1 = h2f(S.y);
    f32x4 bb = reinterpret_cast<const f32x4*>(b1)[q];
    float a0 = fmaxf(fmaf(dv, s0 + t0.x, bb.x), 0.f);
    float a1 = fmaxf(fmaf(dv, s1 + t0.y, bb.y), 0.f);
    float a2 = fmaxf(fmaf(dv, s2 + t1.x, bb.z), 0.f);
    float a3 = fmaxf(fmaf(dv, s3 + t1.y, bb.w), 0.f);
    // fused GEMM2: partial (4 of 16 k-terms) of a1row @ W2 [16x3]
    const float* Wq = W2 + q * 4 * 3;
    float c0 = fmaf(a0, Wq[0], fmaf(a1, Wq[3], fmaf(a2, Wq[6],  a3 * Wq[9])));
    float c1 = fmaf(a0, Wq[1], fmaf(a1, Wq[4], fmaf(a2, Wq[7],  a3 * Wq[10])));
    float c2 = fmaf(a0, Wq[2], fmaf(a1, Wq[5], fmaf(a2, Wq[8],  a3 * Wq[11])));
    // reduce across the 4-lane group (lanes l*4 .. l*4+3 are wave-contiguous)
    c0 += __shfl_xor(c0, 1); c0 += __shfl_xor(c0, 2);
    c1 += __shfl_xor(c1, 1); c1 += __shfl_xor(c1, 2);
    c2 += __shfl_xor(c2, 1); c2 += __shfl_xor(c2, 2);
    if (q == 0) {
        u32x2 o;
        o.x = f2h(dv * c0, dv * c1);
        o.y = f2h(dv * c2, 0.f);
        ntstore(reinterpret_cast<u32x2*>(h2h) + v, o);
    }
}

// ---------------- AGG2: CSR pull, 2 lanes per dst + bias + log_softmax ----------------
__global__ __launch_bounds__(256) void k_agg2(const unsigned int* __restrict__ pairs,
                                              const int* __restrict__ rows,
                                              const float* __restrict__ dinv,
                                              const unsigned int* __restrict__ h2h,
                                              const float* __restrict__ b2,
                                              float* __restrict__ out) {
    int b = blockIdx.x, t = threadIdx.x;
    int half = t & 1;         // stride-2 split of the run
    int l = t >> 1;           // local dst 0..127
    int v = b * 128 + l;
    if (v >= N_NODES) return; // both lanes of a pair exit together
    int e = rows[b * 128 + l];
    int st = b * CAP + (e >> 16);
    int cnt = e & 0xffff;
    const u32x2* h2v = reinterpret_cast<const u32x2*>(h2h);
    float c0 = 0.f, c1 = 0.f, c2 = 0.f;
    int i = half;
    for (; i + 6 < cnt; i += 8) {
        unsigned p0 = ntload(pairs + st + i);
        unsigned p1 = ntload(pairs + st + i + 2);
        unsigned p2 = ntload(pairs + st + i + 4);
        unsigned p3 = ntload(pairs + st + i + 6);
        u32x2 A = h2v[p0 >> 7];
        u32x2 B = h2v[p1 >> 7];
        u32x2 C = h2v[p2 >> 7];
        u32x2 D = h2v[p3 >> 7];
        float2 f01, f2_;
        f01 = h2f(A.x); f2_ = h2f(A.y); c0 += f01.x; c1 += f01.y; c2 += f2_.x;
        f01 = h2f(B.x); f2_ = h2f(B.y); c0 += f01.x; c1 += f01.y; c2 += f2_.x;
        f01 = h2f(C.x); f2_ = h2f(C.y); c0 += f01.x; c1 += f01.y; c2 += f2_.x;
        f01 = h2f(D.x); f2_ = h2f(D.y); c0 += f01.x; c1 += f01.y; c2 += f2_.x;
    }
    for (; i < cnt; i += 2) {
        unsigned p = ntload(pairs + st + i);
        u32x2 A = h2v[p >> 7];
        float2 f01 = h2f(A.x), f2_ = h2f(A.y);
        c0 += f01.x; c1 += f01.y; c2 += f2_.x;
    }
    // combine the stride-2 partials
    c0 += __shfl_xor(c0, 1);
    c1 += __shfl_xor(c1, 1);
    c2 += __shfl_xor(c2, 1);
    if (half == 0) {
        float dv = dinv[v];
        u32x2 hv = h2v[v];                       // self loop (already dv*h2)
        float2 f01 = h2f(hv.x), f2_ = h2f(hv.y);
        float z0 = fmaf(dv, c0 + f01.x, b2[0]);
        float z1 = fmaf(dv, c1 + f01.y, b2[1]);
        float z2 = fmaf(dv, c2 + f2_.x, b2[2]);
        float mx = fmaxf(z0, fmaxf(z1, z2));
        float lse = logf(expf(z0 - mx) + expf(z1 - mx) + expf(z2 - mx));
        out[v * 3 + 0] = z0 - mx - lse;
        out[v * 3 + 1] = z1 - mx - lse;
        out[v * 3 + 2] = z2 - mx - lse;
    }
}

extern "C" void kernel_launch(void* const* d_in, const int* in_sizes, int n_in,
                              void* d_out, int out_size, void* d_ws, size_t ws_size,
                              hipStream_t stream) {
    (void)in_sizes; (void)n_in; (void)out_size; (void)ws_size;
    const float* x  = (const float*)d_in[0];
    const float* W1 = (const float*)d_in[1];
    const float* b1 = (const float*)d_in[2];
    const float* W2 = (const float*)d_in[3];
    const float* b2 = (const float*)d_in[4];
    const int*   ei = (const int*)d_in[5];
    const int* src = ei;
    const int* dst = ei + N_EDGES;
    float* out = (float*)d_out;

    int* ws = (int*)d_ws;
    int*          gcur  = ws + OFF_GCUR;
    float*        dinv  = (float*)(ws + OFF_DINV);
    unsigned int* pairs = (unsigned int*)(ws + OFF_PAIRS);
    int*          rows  = ws + OFF_ROWS;
    unsigned int* h1h   = (unsigned int*)(ws + OFF_H1H);
    unsigned int* h2h   = (unsigned int*)(ws + OFF_H2H);

    k_init <<<(NB + 255) / 256, 256, 0, stream>>>(gcur);
    k_part <<<NBLK_PART, 512, 0, stream>>>(src, dst, gcur, pairs);
    k_sort <<<NB, 512, 0, stream>>>(pairs, gcur, dinv, rows);
    k_gemm1<<<NB, 512, 0, stream>>>(x, W1, dinv, h1h);
    k_agg1 <<<NB, 512, 0, stream>>>(pairs, rows, dinv, h1h, b1, W2, h2h);
    k_agg2 <<<NB, 256, 0, stream>>>(pairs, rows, dinv, h2h, b2, out);
}